// Round 7
// baseline (134.762 us; speedup 1.0000x reference)
//
#include <hip/hip_runtime.h>

#define NN 512
#define DIN 64
#define DH 32
#define HSTR 520   // h_t row stride (pad: 260 dw == 4 mod 32, keeps 16B alignment)

typedef __attribute__((ext_vector_type(8))) short short8;
typedef __attribute__((ext_vector_type(4))) short short4v;
typedef __attribute__((ext_vector_type(4))) float f32x4;

__device__ __forceinline__ float bf2f(unsigned short u) {
    return __uint_as_float(((unsigned)u) << 16);
}
__device__ __forceinline__ unsigned short f2bf(float x) {
    unsigned u = __float_as_uint(x);
    u += 0x7FFF + ((u >> 16) & 1);
    return (unsigned short)(u >> 16);
}

// TWO blocks per (head, batch): each computes full phase-A projection (needed for
// the j-side of all scores) but only HALF the i-rows in phase B. 512 blocks x
// 512 threads -> 2 blocks/CU -> 4 waves/SIMD (was grid-limited to 2 waves/SIMD).
// TOOLCHAIN RULE (verified twice, R2-R4): 1024-thread blocks pin VGPR=64 regardless
// of __launch_bounds__ 2nd arg -> massive scratch spill. Never use 1024-thr blocks;
// never force the allocator with the 2nd arg.
__global__ __launch_bounds__(512) void attn_kernel(
    const float* __restrict__ in_g,    // [B,512,64]
    const float* __restrict__ lin_g,   // [H,64,32]
    const float* __restrict__ asrc_g,  // [H,32]
    const float* __restrict__ atar_g,  // [H,32]
    float* __restrict__ msgs8)         // [B*8][512][32] fp32, slice = b*8+h
{
    __shared__ unsigned short h_t[DH * HSTR];       // 33280 B: h_t[c*HSTR + m] = h[m][c]
    __shared__ float s_arr[NN], e1s[NN], e2s[NN];   // j-side: s, e^s, e^{0.2s}
    __shared__ float cng[NN], e1t[NN], e2t[NN];     // i-side: -t, e^t, e^{0.2t}
    __shared__ float dinv[NN];

    const int t = threadIdx.x;
    const int lane = t & 63, wv = t >> 6;
    const int l15 = lane & 15, quad = lane >> 4;
    // pair same-(h,b) blocks adjacently for L2 reuse of in_g/lin_g
    const int half = blockIdx.x & 1;                // which 256 i-rows this block owns
    const int hIdx = (blockIdx.x >> 1) & 7;
    const int bIdx = blockIdx.x >> 4;

    const float as_lo = asrc_g[hIdx * 32 + l15];
    const float as_hi = asrc_g[hIdx * 32 + l15 + 16];
    const float at_lo = atar_g[hIdx * 32 + l15];
    const float at_hi = atar_g[hIdx * 32 + l15 + 16];

    // ---------- Phase A: FULL projection h = x @ W via MFMA (all 512 rows) ----------
    short8 bfrag[2][2];
    {
        const float* lp = lin_g + hIdx * (DIN * DH);
        for (int nt = 0; nt < 2; ++nt)
            for (int ks = 0; ks < 2; ++ks)
                #pragma unroll
                for (int j = 0; j < 8; ++j)
                    bfrag[nt][ks][j] = (short)f2bf(lp[(ks * 32 + quad * 8 + j) * DH + l15 + nt * 16]);
    }
    const float* xb = in_g + (size_t)bIdx * (NN * DIN);
    for (int mi = 0; mi < 4; ++mi) {
        int mt = wv * 4 + mi;
        int row = mt * 16 + l15;
        const float* rp = xb + row * DIN + quad * 8;
        f32x4 x0 = *((const f32x4*)rp);
        f32x4 x1 = *((const f32x4*)(rp + 4));
        f32x4 x2 = *((const f32x4*)(rp + 32));
        f32x4 x3 = *((const f32x4*)(rp + 36));
        short8 a0, a1;
        #pragma unroll
        for (int j = 0; j < 4; ++j) {
            a0[j]     = (short)f2bf(x0[j]);
            a0[4 + j] = (short)f2bf(x1[j]);
            a1[j]     = (short)f2bf(x2[j]);
            a1[4 + j] = (short)f2bf(x3[j]);
        }
        f32x4 c0 = {0.f, 0.f, 0.f, 0.f}, c1 = {0.f, 0.f, 0.f, 0.f};
        c0 = __builtin_amdgcn_mfma_f32_16x16x32_bf16(a0, bfrag[0][0], c0, 0, 0, 0);
        c0 = __builtin_amdgcn_mfma_f32_16x16x32_bf16(a1, bfrag[0][1], c0, 0, 0, 0);
        c1 = __builtin_amdgcn_mfma_f32_16x16x32_bf16(a0, bfrag[1][0], c1, 0, 0, 0);
        c1 = __builtin_amdgcn_mfma_f32_16x16x32_bf16(a1, bfrag[1][1], c1, 0, 0, 0);
        float ps[4], pt[4];
        #pragma unroll
        for (int r = 0; r < 4; ++r) {
            int m = mt * 16 + quad * 4 + r;
            h_t[l15 * HSTR + m]        = f2bf(c0[r]);
            h_t[(l15 + 16) * HSTR + m] = f2bf(c1[r]);
            ps[r] = c0[r] * as_lo + c1[r] * as_hi;
            pt[r] = c0[r] * at_lo + c1[r] * at_hi;
        }
        #pragma unroll
        for (int off = 1; off <= 8; off <<= 1) {
            #pragma unroll
            for (int r = 0; r < 4; ++r) {
                ps[r] += __shfl_xor(ps[r], off, 64);
                pt[r] += __shfl_xor(pt[r], off, 64);
            }
        }
        if (l15 < 4) {
            int r = l15;
            int m = mt * 16 + quad * 4 + r;
            float s = ps[r], tt = pt[r];
            s_arr[m] = s;
            e1s[m] = expf(s);   e2s[m] = expf(0.2f * s);
            cng[m] = -tt;
            e1t[m] = expf(tt);  e2t[m] = expf(0.2f * tt);
        }
    }
    __syncthreads();

    // ---------- Phase B: HALF the i-rows (2 row-tiles/wave) ----------
    float cn[2], t1[2], t2[2];
    int iR[2], rtile[2];
    #pragma unroll
    for (int rt = 0; rt < 2; ++rt) {
        rtile[rt] = half * 16 + wv * 2 + rt;        // row-tile in [0,32)
        int rw = rtile[rt] * 16 + l15;
        iR[rt] = rw;
        cn[rt] = cng[rw]; t1[rt] = e1t[rw]; t2[rt] = e2t[rw];
    }
    f32x4 acc[2][2];
    float dacc[2];
    #pragma unroll
    for (int rt = 0; rt < 2; ++rt) {
        acc[rt][0] = (f32x4){0.f, 0.f, 0.f, 0.f};
        acc[rt][1] = (f32x4){0.f, 0.f, 0.f, 0.f};
        dacc[rt] = 0.f;
    }

    for (int kb = 0; kb < 16; ++kb) {
        const int j0 = kb * 32 + quad * 8;
        f32x4 sv0 = *(const f32x4*)&s_arr[j0], sv1 = *(const f32x4*)&s_arr[j0 + 4];
        f32x4 ev0 = *(const f32x4*)&e1s[j0],   ev1 = *(const f32x4*)&e1s[j0 + 4];
        f32x4 fv0 = *(const f32x4*)&e2s[j0],   fv1 = *(const f32x4*)&e2s[j0 + 4];
        short8 b0 = *(const short8*)&h_t[l15 * HSTR + j0];
        short8 b1 = *(const short8*)&h_t[(l15 + 16) * HSTR + j0];
        #pragma unroll
        for (int rt = 0; rt < 2; ++rt) {
            const bool selfkb = (kb == (rtile[rt] >> 1));
            float w8[8];
            #pragma unroll
            for (int jj = 0; jj < 8; ++jj) {
                float sj = (jj < 4) ? sv0[jj & 3] : sv1[jj & 3];
                float e1 = (jj < 4) ? ev0[jj & 3] : ev1[jj & 3];
                float e2 = (jj < 4) ? fv0[jj & 3] : fv1[jj & 3];
                float w = (sj > cn[rt]) ? t1[rt] * e1 : t2[rt] * e2;
                if (selfkb && (j0 + jj == iR[rt])) w = 0.f;
                w8[jj] = w;
            }
            // tree-sum denominator contribution (breaks 8-deep serial add chain)
            dacc[rt] += ((w8[0] + w8[1]) + (w8[2] + w8[3]))
                      + ((w8[4] + w8[5]) + (w8[6] + w8[7]));
            union { unsigned u[4]; short8 s8; } au;
            #pragma unroll
            for (int pp = 0; pp < 4; ++pp) {
                unsigned lo = __float_as_uint(w8[2 * pp])     + 0x8000u;
                unsigned hi = __float_as_uint(w8[2 * pp + 1]) + 0x8000u;
                au.u[pp] = (lo >> 16) | (hi & 0xffff0000u);
            }
            acc[rt][0] = __builtin_amdgcn_mfma_f32_16x16x32_bf16(au.s8, b0, acc[rt][0], 0, 0, 0);
            acc[rt][1] = __builtin_amdgcn_mfma_f32_16x16x32_bf16(au.s8, b1, acc[rt][1], 0, 0, 0);
        }
    }

    // denominator: reduce the 4 quads (same row lives in lanes sharing l15)
    #pragma unroll
    for (int rt = 0; rt < 2; ++rt) {
        float D = dacc[rt];
        D += __shfl_xor(D, 16, 64);
        D += __shfl_xor(D, 32, 64);
        if (quad == 0) dinv[iR[rt]] = 0.125f / D;   // fold 1/H; same-wave read below
    }

    float* mbase = msgs8 + ((size_t)bIdx * 8 + hIdx) * (NN * DH);
    #pragma unroll
    for (int rt = 0; rt < 2; ++rt) {
        #pragma unroll
        for (int halfc = 0; halfc < 2; ++halfc) {
            #pragma unroll
            for (int r = 0; r < 4; ++r) {
                int row = rtile[rt] * 16 + quad * 4 + r;
                mbase[row * DH + halfc * 16 + l15] = acc[rt][halfc][r] * dinv[row];
            }
        }
    }
}

// GRU-style gated update. 512 blocks x 256 threads, 32 rows/block (4 rows/thread).
// Occupancy raised via MORE BLOCKS (2 blocks/CU = 2 waves/SIMD), NOT bigger blocks
// (1024-thr blocks pin VGPR=64 -> spill, see R4).
__global__ __launch_bounds__(256) void gru_kernel(
    const float* __restrict__ in_g,
    const float* __restrict__ hid_g,
    const float* __restrict__ bias_g,
    const float* __restrict__ Whr, const float* __restrict__ Whi,
    const float* __restrict__ Whm,
    const float* __restrict__ Wir, const float* __restrict__ bir,
    const float* __restrict__ Wii, const float* __restrict__ bii,
    const float* __restrict__ Win, const float* __restrict__ bin_,
    const float* __restrict__ msgs8,   // [B*8][512][32], slice = b*8+h
    float* __restrict__ out_g)
{
    __shared__ float xs[32 * 100];                // cols 0..63 = x, 64..95 = tanh(msum+bias)
    __shared__ unsigned short WtL[3 * 32 * 100];  // Wt[g][k][d] bf16 (96 d's used)

    const int t = threadIdx.x;
    const int rowbase = blockIdx.x * 32;          // 512 blocks x 32 rows
    const int bslice = blockIdx.x >> 4;           // batch of this block (32 | 512)
    const int r0 = (blockIdx.x & 15) * 32;        // row offset within batch

    // stage x: 32 rows x 64 cols, f32x4 (512 vec-ops, 2 iters)
    for (int idx = t; idx < 512; idx += 256) {
        int row = idx >> 4, dq = idx & 15;
        f32x4 v = *(const f32x4*)&in_g[(size_t)(rowbase + row) * 64 + dq * 4];
        *(f32x4*)&xs[row * 100 + dq * 4] = v;
    }
    // msgv = tanh(sum_h msgs8[b*8+h] + bias), vectorized f32x4 (1 iter)
    {
        int row = t >> 3, kq = t & 7;             // 256 = 32 rows x 8 k-quads
        size_t base = (size_t)bslice * (8 * NN * DH) + (size_t)(r0 + row) * DH + kq * 4;
        f32x4 s = {0.f, 0.f, 0.f, 0.f};
        #pragma unroll
        for (int h = 0; h < 8; ++h) {
            f32x4 v = *(const f32x4*)&msgs8[base + (size_t)h * (NN * DH)];
            s.x += v.x; s.y += v.y; s.z += v.z; s.w += v.w;
        }
        const float* bg = bias_g + kq * 4;
        float* dst = &xs[row * 100 + 64 + kq * 4];
        dst[0] = tanhf(s.x + bg[0]);
        dst[1] = tanhf(s.y + bg[1]);
        dst[2] = tanhf(s.z + bg[2]);
        dst[3] = tanhf(s.w + bg[3]);
    }
    // stage weights: 3 gates x 3072, simple loops (no div/mod)
    for (int idx = t; idx < 3072; idx += 256) {
        int d = idx >> 5, k2 = idx & 31;
        WtL[(0 * 32 + k2) * 100 + d] = f2bf((d < 64) ? Wir[d * 32 + k2] : Whr[(d - 64) * 32 + k2]);
        WtL[(1 * 32 + k2) * 100 + d] = f2bf((d < 64) ? Wii[d * 32 + k2] : Whi[(d - 64) * 32 + k2]);
        WtL[(2 * 32 + k2) * 100 + d] = f2bf((d < 64) ? Win[d * 32 + k2] : Whm[(d - 64) * 32 + k2]);
    }
    __syncthreads();

    const int k = t & 31, rg = t >> 5;            // rg in 0..7, 4 rows each
    const unsigned short* wp0 = &WtL[(0 * 32 + k) * 100];
    const unsigned short* wp1 = &WtL[(1 * 32 + k) * 100];
    const unsigned short* wp2 = &WtL[(2 * 32 + k) * 100];

    float pr[4], pi[4], xn[4], hm[4];
    #pragma unroll
    for (int r = 0; r < 4; ++r) { pr[r] = 0.f; pi[r] = 0.f; xn[r] = 0.f; hm[r] = 0.f; }

    for (int d0 = 0; d0 < 64; d0 += 4) {
        short4v wr4 = *(const short4v*)&wp0[d0];
        short4v wi4 = *(const short4v*)&wp1[d0];
        short4v wn4 = *(const short4v*)&wp2[d0];
        float wr[4], wi[4], wn[4];
        #pragma unroll
        for (int jj = 0; jj < 4; ++jj) {
            wr[jj] = bf2f((unsigned short)wr4[jj]);
            wi[jj] = bf2f((unsigned short)wi4[jj]);
            wn[jj] = bf2f((unsigned short)wn4[jj]);
        }
        #pragma unroll
        for (int r = 0; r < 4; ++r) {
            f32x4 xv = *(const f32x4*)&xs[(rg * 4 + r) * 100 + d0];
            #pragma unroll
            for (int jj = 0; jj < 4; ++jj) {
                pr[r] += xv[jj] * wr[jj];
                pi[r] += xv[jj] * wi[jj];
                xn[r] += xv[jj] * wn[jj];
            }
        }
    }
    for (int d0 = 64; d0 < 96; d0 += 4) {
        short4v wr4 = *(const short4v*)&wp0[d0];
        short4v wi4 = *(const short4v*)&wp1[d0];
        short4v wn4 = *(const short4v*)&wp2[d0];
        float wr[4], wi[4], wn[4];
        #pragma unroll
        for (int jj = 0; jj < 4; ++jj) {
            wr[jj] = bf2f((unsigned short)wr4[jj]);
            wi[jj] = bf2f((unsigned short)wi4[jj]);
            wn[jj] = bf2f((unsigned short)wn4[jj]);
        }
        #pragma unroll
        for (int r = 0; r < 4; ++r) {
            f32x4 xv = *(const f32x4*)&xs[(rg * 4 + r) * 100 + d0];
            #pragma unroll
            for (int jj = 0; jj < 4; ++jj) {
                pr[r] += xv[jj] * wr[jj];
                pi[r] += xv[jj] * wi[jj];
                hm[r] += xv[jj] * wn[jj];
            }
        }
    }

    const float bir_k = bir[k], bii_k = bii[k], bin_k = bin_[k];
    #pragma unroll
    for (int r = 0; r < 4; ++r) {
        int row = rowbase + rg * 4 + r;
        float m  = 1.f / (1.f + expf(-(pr[r] + bir_k)));
        float ig = 1.f / (1.f + expf(-(pi[r] + bii_k)));
        float nn = tanhf(xn[r] + bin_k + m * hm[r]);
        float ho = hid_g[(size_t)row * 32 + k];
        out_g[(size_t)row * 32 + k] = ig * nn + (1.f - ig) * ho;
    }
}

extern "C" void kernel_launch(void* const* d_in, const int* in_sizes, int n_in,
                              void* d_out, int out_size, void* d_ws, size_t ws_size,
                              hipStream_t stream)
{
    const float* inputs = (const float*)d_in[0];
    const float* hidden = (const float*)d_in[1];
    const float* linear = (const float*)d_in[2];
    const float* bias   = (const float*)d_in[3];
    const float* asrc   = (const float*)d_in[4];
    const float* atar   = (const float*)d_in[5];
    const float* Whr    = (const float*)d_in[6];
    const float* Whi    = (const float*)d_in[7];
    const float* Whm    = (const float*)d_in[8];
    const float* Wir    = (const float*)d_in[9];
    const float* bir    = (const float*)d_in[10];
    const float* Wii    = (const float*)d_in[11];
    const float* bii    = (const float*)d_in[12];
    const float* Win    = (const float*)d_in[13];
    const float* bin_   = (const float*)d_in[14];

    float* msgs8 = (float*)d_ws;   // [B*8][512][32] fp32, 16 MB
    attn_kernel<<<dim3(512), dim3(512), 0, stream>>>(inputs, linear, asrc, atar, msgs8);
    gru_kernel<<<dim3(512), dim3(256), 0, stream>>>(inputs, hidden, bias,
                                                    Whr, Whi, Whm,
                                                    Wir, bir, Wii, bii, Win, bin_,
                                                    msgs8, (float*)d_out);
}

// Round 8
// 123.126 us; speedup vs baseline: 1.0945x; 1.0945x over previous
//
#include <hip/hip_runtime.h>

#define NN 512
#define DIN 64
#define DH 32
#define HSTR 520   // h_t row stride (pad: 260 dw == 4 mod 32, keeps 16B alignment)

typedef __attribute__((ext_vector_type(8))) short short8;
typedef __attribute__((ext_vector_type(4))) short short4v;
typedef __attribute__((ext_vector_type(4))) float f32x4;

__device__ __forceinline__ float bf2f(unsigned short u) {
    return __uint_as_float(((unsigned)u) << 16);
}
__device__ __forceinline__ unsigned short f2bf(float x) {
    unsigned u = __float_as_uint(x);
    u += 0x7FFF + ((u >> 16) & 1);
    return (unsigned short)(u >> 16);
}

// One block per (head, batch). 512 threads = 8 waves. R5-proven grid (126us total);
// the R7 2-block phase-B split regressed (-8.7us: doubled phase-A work).
// TOOLCHAIN RULE (verified twice, R2-R4): 1024-thread blocks pin VGPR=64 regardless
// of __launch_bounds__ 2nd arg -> massive scratch spill. Never use 1024-thr blocks.
// Phase-B VALU diet (R7 counters: VALUBusy 49%, MfmaUtil 4.6% -> VALU-issue-bound):
//  (1) exp(leakyrelu(s+t)) == max(e^t*e^s, e^0.2t*e^0.2s)  -> v_max replaces
//      cmp+cndmask, and s_arr/cng LDS arrays vanish.
//  (2) v_cvt_pk_bf16_f32 packs 2 fp32->bf16x2 in 1 inst (was ~5 bit-twiddle ops).
__global__ __launch_bounds__(512) void attn_kernel(
    const float* __restrict__ in_g,    // [B,512,64]
    const float* __restrict__ lin_g,   // [H,64,32]
    const float* __restrict__ asrc_g,  // [H,32]
    const float* __restrict__ atar_g,  // [H,32]
    float* __restrict__ msgs8)         // [B*8][512][32] fp32, slice = blockIdx.x
{
    __shared__ unsigned short h_t[DH * HSTR];       // 33280 B: h_t[c*HSTR + m] = h[m][c]
    __shared__ float e1s[NN], e2s[NN];              // j-side: e^s, e^{0.2s}
    __shared__ float e1t[NN], e2t[NN];              // i-side: e^t, e^{0.2t}
    __shared__ float dinv[NN];

    const int t = threadIdx.x;
    const int lane = t & 63, wv = t >> 6;
    const int l15 = lane & 15, quad = lane >> 4;
    const int hIdx = blockIdx.x & 7, bIdx = blockIdx.x >> 3;

    const float as_lo = asrc_g[hIdx * 32 + l15];
    const float as_hi = asrc_g[hIdx * 32 + l15 + 16];
    const float at_lo = atar_g[hIdx * 32 + l15];
    const float at_hi = atar_g[hIdx * 32 + l15 + 16];

    // ---------- Phase A: projection h = x @ W via MFMA ----------
    short8 bfrag[2][2];
    {
        const float* lp = lin_g + hIdx * (DIN * DH);
        for (int nt = 0; nt < 2; ++nt)
            for (int ks = 0; ks < 2; ++ks)
                #pragma unroll
                for (int j = 0; j < 8; ++j)
                    bfrag[nt][ks][j] = (short)f2bf(lp[(ks * 32 + quad * 8 + j) * DH + l15 + nt * 16]);
    }
    const float* xb = in_g + (size_t)bIdx * (NN * DIN);
    for (int mi = 0; mi < 4; ++mi) {
        int mt = wv * 4 + mi;
        int row = mt * 16 + l15;
        const float* rp = xb + row * DIN + quad * 8;
        f32x4 x0 = *((const f32x4*)rp);
        f32x4 x1 = *((const f32x4*)(rp + 4));
        f32x4 x2 = *((const f32x4*)(rp + 32));
        f32x4 x3 = *((const f32x4*)(rp + 36));
        short8 a0, a1;
        #pragma unroll
        for (int j = 0; j < 4; ++j) {
            a0[j]     = (short)f2bf(x0[j]);
            a0[4 + j] = (short)f2bf(x1[j]);
            a1[j]     = (short)f2bf(x2[j]);
            a1[4 + j] = (short)f2bf(x3[j]);
        }
        f32x4 c0 = {0.f, 0.f, 0.f, 0.f}, c1 = {0.f, 0.f, 0.f, 0.f};
        c0 = __builtin_amdgcn_mfma_f32_16x16x32_bf16(a0, bfrag[0][0], c0, 0, 0, 0);
        c0 = __builtin_amdgcn_mfma_f32_16x16x32_bf16(a1, bfrag[0][1], c0, 0, 0, 0);
        c1 = __builtin_amdgcn_mfma_f32_16x16x32_bf16(a0, bfrag[1][0], c1, 0, 0, 0);
        c1 = __builtin_amdgcn_mfma_f32_16x16x32_bf16(a1, bfrag[1][1], c1, 0, 0, 0);
        float ps[4], pt[4];
        #pragma unroll
        for (int r = 0; r < 4; ++r) {
            int m = mt * 16 + quad * 4 + r;
            h_t[l15 * HSTR + m]        = f2bf(c0[r]);
            h_t[(l15 + 16) * HSTR + m] = f2bf(c1[r]);
            ps[r] = c0[r] * as_lo + c1[r] * as_hi;
            pt[r] = c0[r] * at_lo + c1[r] * at_hi;
        }
        #pragma unroll
        for (int off = 1; off <= 8; off <<= 1) {
            #pragma unroll
            for (int r = 0; r < 4; ++r) {
                ps[r] += __shfl_xor(ps[r], off, 64);
                pt[r] += __shfl_xor(pt[r], off, 64);
            }
        }
        if (l15 < 4) {
            int r = l15;
            int m = mt * 16 + quad * 4 + r;
            float s = ps[r], tt = pt[r];
            e1s[m] = expf(s);   e2s[m] = expf(0.2f * s);
            e1t[m] = expf(tt);  e2t[m] = expf(0.2f * tt);
        }
    }
    __syncthreads();

    // ---------- Phase B: numerator MFMA (w built in-register) + fp32 denominator ----------
    float t1[4], t2[4];
    int iR[4];
    #pragma unroll
    for (int rt = 0; rt < 4; ++rt) {
        int rw = (wv * 4 + rt) * 16 + l15;
        iR[rt] = rw;
        t1[rt] = e1t[rw]; t2[rt] = e2t[rw];
    }
    f32x4 acc[4][2];
    float dacc[4];
    #pragma unroll
    for (int rt = 0; rt < 4; ++rt) {
        acc[rt][0] = (f32x4){0.f, 0.f, 0.f, 0.f};
        acc[rt][1] = (f32x4){0.f, 0.f, 0.f, 0.f};
        dacc[rt] = 0.f;
    }

    for (int kb = 0; kb < 16; ++kb) {
        const int j0 = kb * 32 + quad * 8;
        f32x4 ev0 = *(const f32x4*)&e1s[j0], ev1 = *(const f32x4*)&e1s[j0 + 4];
        f32x4 fv0 = *(const f32x4*)&e2s[j0], fv1 = *(const f32x4*)&e2s[j0 + 4];
        short8 b0 = *(const short8*)&h_t[l15 * HSTR + j0];
        short8 b1 = *(const short8*)&h_t[(l15 + 16) * HSTR + j0];
        #pragma unroll
        for (int rt = 0; rt < 4; ++rt) {
            const bool selfkb = (kb == ((wv * 4 + rt) >> 1));
            float w8[8];
            #pragma unroll
            for (int jj = 0; jj < 8; ++jj) {
                float e1 = (jj < 4) ? ev0[jj & 3] : ev1[jj & 3];
                float e2 = (jj < 4) ? fv0[jj & 3] : fv1[jj & 3];
                // exp(leakyrelu(s+t)) = max(e^t*e^s, e^{0.2t}*e^{0.2s})
                float w = fmaxf(t1[rt] * e1, t2[rt] * e2);
                if (selfkb && (j0 + jj == iR[rt])) w = 0.f;
                w8[jj] = w;
            }
            // tree-sum denominator contribution (breaks 8-deep serial add chain)
            dacc[rt] += ((w8[0] + w8[1]) + (w8[2] + w8[3]))
                      + ((w8[4] + w8[5]) + (w8[6] + w8[7]));
            union { unsigned u[4]; short8 s8; } au;
            #pragma unroll
            for (int pp = 0; pp < 4; ++pp) {
                // dst.lo16 = bf16(src0), dst.hi16 = bf16(src1)  (RNE)
                asm("v_cvt_pk_bf16_f32 %0, %1, %2"
                    : "=v"(au.u[pp])
                    : "v"(w8[2 * pp]), "v"(w8[2 * pp + 1]));
            }
            acc[rt][0] = __builtin_amdgcn_mfma_f32_16x16x32_bf16(au.s8, b0, acc[rt][0], 0, 0, 0);
            acc[rt][1] = __builtin_amdgcn_mfma_f32_16x16x32_bf16(au.s8, b1, acc[rt][1], 0, 0, 0);
        }
    }

    // denominator: reduce the 4 quads (same row lives in lanes sharing l15)
    #pragma unroll
    for (int rt = 0; rt < 4; ++rt) {
        float D = dacc[rt];
        D += __shfl_xor(D, 16, 64);
        D += __shfl_xor(D, 32, 64);
        if (quad == 0) dinv[iR[rt]] = 0.125f / D;   // fold 1/H; same-wave read below
    }

    float* mbase = msgs8 + (size_t)blockIdx.x * (NN * DH);
    #pragma unroll
    for (int rt = 0; rt < 4; ++rt) {
        #pragma unroll
        for (int half = 0; half < 2; ++half) {
            #pragma unroll
            for (int r = 0; r < 4; ++r) {
                int row = (wv * 4 + rt) * 16 + quad * 4 + r;
                mbase[row * DH + half * 16 + l15] = acc[rt][half][r] * dinv[row];
            }
        }
    }
}

// GRU-style gated update. 512 blocks x 256 threads, 32 rows/block (4 rows/thread).
// Occupancy raised via MORE BLOCKS (2 blocks/CU = 2 waves/SIMD), NOT bigger blocks
// (1024-thr blocks pin VGPR=64 -> spill, see R4).
__global__ __launch_bounds__(256) void gru_kernel(
    const float* __restrict__ in_g,
    const float* __restrict__ hid_g,
    const float* __restrict__ bias_g,
    const float* __restrict__ Whr, const float* __restrict__ Whi,
    const float* __restrict__ Whm,
    const float* __restrict__ Wir, const float* __restrict__ bir,
    const float* __restrict__ Wii, const float* __restrict__ bii,
    const float* __restrict__ Win, const float* __restrict__ bin_,
    const float* __restrict__ msgs8,   // [B*8][512][32], slice = b*8+h
    float* __restrict__ out_g)
{
    __shared__ float xs[32 * 100];                // cols 0..63 = x, 64..95 = tanh(msum+bias)
    __shared__ unsigned short WtL[3 * 32 * 100];  // Wt[g][k][d] bf16 (96 d's used)

    const int t = threadIdx.x;
    const int rowbase = blockIdx.x * 32;          // 512 blocks x 32 rows
    const int bslice = blockIdx.x >> 4;           // batch of this block (32 | 512)
    const int r0 = (blockIdx.x & 15) * 32;        // row offset within batch

    // stage x: 32 rows x 64 cols, f32x4 (512 vec-ops, 2 iters)
    for (int idx = t; idx < 512; idx += 256) {
        int row = idx >> 4, dq = idx & 15;
        f32x4 v = *(const f32x4*)&in_g[(size_t)(rowbase + row) * 64 + dq * 4];
        *(f32x4*)&xs[row * 100 + dq * 4] = v;
    }
    // msgv = tanh(sum_h msgs8[b*8+h] + bias), vectorized f32x4 (1 iter)
    {
        int row = t >> 3, kq = t & 7;             // 256 = 32 rows x 8 k-quads
        size_t base = (size_t)bslice * (8 * NN * DH) + (size_t)(r0 + row) * DH + kq * 4;
        f32x4 s = {0.f, 0.f, 0.f, 0.f};
        #pragma unroll
        for (int h = 0; h < 8; ++h) {
            f32x4 v = *(const f32x4*)&msgs8[base + (size_t)h * (NN * DH)];
            s.x += v.x; s.y += v.y; s.z += v.z; s.w += v.w;
        }
        const float* bg = bias_g + kq * 4;
        float* dst = &xs[row * 100 + 64 + kq * 4];
        dst[0] = tanhf(s.x + bg[0]);
        dst[1] = tanhf(s.y + bg[1]);
        dst[2] = tanhf(s.z + bg[2]);
        dst[3] = tanhf(s.w + bg[3]);
    }
    // stage weights: 3 gates x 3072, simple loops (no div/mod)
    for (int idx = t; idx < 3072; idx += 256) {
        int d = idx >> 5, k2 = idx & 31;
        WtL[(0 * 32 + k2) * 100 + d] = f2bf((d < 64) ? Wir[d * 32 + k2] : Whr[(d - 64) * 32 + k2]);
        WtL[(1 * 32 + k2) * 100 + d] = f2bf((d < 64) ? Wii[d * 32 + k2] : Whi[(d - 64) * 32 + k2]);
        WtL[(2 * 32 + k2) * 100 + d] = f2bf((d < 64) ? Win[d * 32 + k2] : Whm[(d - 64) * 32 + k2]);
    }
    __syncthreads();

    const int k = t & 31, rg = t >> 5;            // rg in 0..7, 4 rows each
    const unsigned short* wp0 = &WtL[(0 * 32 + k) * 100];
    const unsigned short* wp1 = &WtL[(1 * 32 + k) * 100];
    const unsigned short* wp2 = &WtL[(2 * 32 + k) * 100];

    float pr[4], pi[4], xn[4], hm[4];
    #pragma unroll
    for (int r = 0; r < 4; ++r) { pr[r] = 0.f; pi[r] = 0.f; xn[r] = 0.f; hm[r] = 0.f; }

    for (int d0 = 0; d0 < 64; d0 += 4) {
        short4v wr4 = *(const short4v*)&wp0[d0];
        short4v wi4 = *(const short4v*)&wp1[d0];
        short4v wn4 = *(const short4v*)&wp2[d0];
        float wr[4], wi[4], wn[4];
        #pragma unroll
        for (int jj = 0; jj < 4; ++jj) {
            wr[jj] = bf2f((unsigned short)wr4[jj]);
            wi[jj] = bf2f((unsigned short)wi4[jj]);
            wn[jj] = bf2f((unsigned short)wn4[jj]);
        }
        #pragma unroll
        for (int r = 0; r < 4; ++r) {
            f32x4 xv = *(const f32x4*)&xs[(rg * 4 + r) * 100 + d0];
            #pragma unroll
            for (int jj = 0; jj < 4; ++jj) {
                pr[r] += xv[jj] * wr[jj];
                pi[r] += xv[jj] * wi[jj];
                xn[r] += xv[jj] * wn[jj];
            }
        }
    }
    for (int d0 = 64; d0 < 96; d0 += 4) {
        short4v wr4 = *(const short4v*)&wp0[d0];
        short4v wi4 = *(const short4v*)&wp1[d0];
        short4v wn4 = *(const short4v*)&wp2[d0];
        float wr[4], wi[4], wn[4];
        #pragma unroll
        for (int jj = 0; jj < 4; ++jj) {
            wr[jj] = bf2f((unsigned short)wr4[jj]);
            wi[jj] = bf2f((unsigned short)wi4[jj]);
            wn[jj] = bf2f((unsigned short)wn4[jj]);
        }
        #pragma unroll
        for (int r = 0; r < 4; ++r) {
            f32x4 xv = *(const f32x4*)&xs[(rg * 4 + r) * 100 + d0];
            #pragma unroll
            for (int jj = 0; jj < 4; ++jj) {
                pr[r] += xv[jj] * wr[jj];
                pi[r] += xv[jj] * wi[jj];
                hm[r] += xv[jj] * wn[jj];
            }
        }
    }

    const float bir_k = bir[k], bii_k = bii[k], bin_k = bin_[k];
    #pragma unroll
    for (int r = 0; r < 4; ++r) {
        int row = rowbase + rg * 4 + r;
        float m  = 1.f / (1.f + expf(-(pr[r] + bir_k)));
        float ig = 1.f / (1.f + expf(-(pi[r] + bii_k)));
        float nn = tanhf(xn[r] + bin_k + m * hm[r]);
        float ho = hid_g[(size_t)row * 32 + k];
        out_g[(size_t)row * 32 + k] = ig * nn + (1.f - ig) * ho;
    }
}

extern "C" void kernel_launch(void* const* d_in, const int* in_sizes, int n_in,
                              void* d_out, int out_size, void* d_ws, size_t ws_size,
                              hipStream_t stream)
{
    const float* inputs = (const float*)d_in[0];
    const float* hidden = (const float*)d_in[1];
    const float* linear = (const float*)d_in[2];
    const float* bias   = (const float*)d_in[3];
    const float* asrc   = (const float*)d_in[4];
    const float* atar   = (const float*)d_in[5];
    const float* Whr    = (const float*)d_in[6];
    const float* Whi    = (const float*)d_in[7];
    const float* Whm    = (const float*)d_in[8];
    const float* Wir    = (const float*)d_in[9];
    const float* bir    = (const float*)d_in[10];
    const float* Wii    = (const float*)d_in[11];
    const float* bii    = (const float*)d_in[12];
    const float* Win    = (const float*)d_in[13];
    const float* bin_   = (const float*)d_in[14];

    float* msgs8 = (float*)d_ws;   // [B*8][512][32] fp32, 16 MB
    attn_kernel<<<dim3(256), dim3(512), 0, stream>>>(inputs, linear, asrc, atar, msgs8);
    gru_kernel<<<dim3(512), dim3(256), 0, stream>>>(inputs, hidden, bias,
                                                    Whr, Whi, Whm,
                                                    Wir, bir, Wii, bii, Win, bin_,
                                                    msgs8, (float*)d_out);
}

// Round 9
// 119.493 us; speedup vs baseline: 1.1278x; 1.0304x over previous
//
#include <hip/hip_runtime.h>

#define NN 512
#define DIN 64
#define DH 32
#define HSTR 520   // h_t row stride (pad: 260 dw == 4 mod 32, keeps 16B alignment)

typedef __attribute__((ext_vector_type(8))) short short8;
typedef __attribute__((ext_vector_type(4))) short short4v;
typedef __attribute__((ext_vector_type(4))) float f32x4;

__device__ __forceinline__ float bf2f(unsigned short u) {
    return __uint_as_float(((unsigned)u) << 16);
}
__device__ __forceinline__ unsigned short f2bf(float x) {
    unsigned u = __float_as_uint(x);
    u += 0x7FFF + ((u >> 16) & 1);
    return (unsigned short)(u >> 16);
}
// packed RNE f32x2 -> bf16x2 (1 VALU op vs ~4 for scalar f2bf; same rounding)
__device__ __forceinline__ unsigned cvt_pk_bf16(float lo, float hi) {
    unsigned r;
    asm("v_cvt_pk_bf16_f32 %0, %1, %2" : "=v"(r) : "v"(lo), "v"(hi));
    return r;
}

// One block per (head, batch). 512 threads = 8 waves. R5-proven grid.
// TOOLCHAIN RULE (verified twice, R2-R4): 1024-thread blocks pin VGPR=64 regardless
// of __launch_bounds__ 2nd arg -> massive scratch spill. Never use 1024-thr blocks.
// VALU diet (R7: VALUBusy 49%, MfmaUtil 4.6% -> issue-bound; R8 cut confirmed -3us):
//  (1) exp(leakyrelu(s+t)) == max(e^t*e^s, e^0.2t*e^0.2s)   [R8, confirmed]
//  (2) v_cvt_pk_bf16_f32 for all f32->bf16 packing            [R8 phase-B; R9 phase-A]
//  (3) self-mask peeled: per-jj cmp/cndmask only on the 2/16 kb's where it can hit
__global__ __launch_bounds__(512) void attn_kernel(
    const float* __restrict__ in_g,    // [B,512,64]
    const float* __restrict__ lin_g,   // [H,64,32]
    const float* __restrict__ asrc_g,  // [H,32]
    const float* __restrict__ atar_g,  // [H,32]
    float* __restrict__ msgs8)         // [B*8][512][32] fp32, slice = blockIdx.x
{
    __shared__ unsigned short h_t[DH * HSTR];       // 33280 B: h_t[c*HSTR + m] = h[m][c]
    __shared__ float e1s[NN], e2s[NN];              // j-side: e^s, e^{0.2s}
    __shared__ float e1t[NN], e2t[NN];              // i-side: e^t, e^{0.2t}
    __shared__ float dinv[NN];

    const int t = threadIdx.x;
    const int lane = t & 63, wv = t >> 6;
    const int l15 = lane & 15, quad = lane >> 4;
    const int hIdx = blockIdx.x & 7, bIdx = blockIdx.x >> 3;

    const float as_lo = asrc_g[hIdx * 32 + l15];
    const float as_hi = asrc_g[hIdx * 32 + l15 + 16];
    const float at_lo = atar_g[hIdx * 32 + l15];
    const float at_hi = atar_g[hIdx * 32 + l15 + 16];

    // ---------- Phase A: projection h = x @ W via MFMA ----------
    short8 bfrag[2][2];
    {
        const float* lp = lin_g + hIdx * (DIN * DH);
        for (int nt = 0; nt < 2; ++nt)
            for (int ks = 0; ks < 2; ++ks) {
                union { unsigned u[4]; short8 s8; } bu;
                #pragma unroll
                for (int jp = 0; jp < 4; ++jp) {
                    float lo = lp[(ks * 32 + quad * 8 + 2 * jp)     * DH + l15 + nt * 16];
                    float hi = lp[(ks * 32 + quad * 8 + 2 * jp + 1) * DH + l15 + nt * 16];
                    bu.u[jp] = cvt_pk_bf16(lo, hi);
                }
                bfrag[nt][ks] = bu.s8;
            }
    }
    const float* xb = in_g + (size_t)bIdx * (NN * DIN);
    for (int mi = 0; mi < 4; ++mi) {
        int mt = wv * 4 + mi;
        int row = mt * 16 + l15;
        const float* rp = xb + row * DIN + quad * 8;
        f32x4 x0 = *((const f32x4*)rp);
        f32x4 x1 = *((const f32x4*)(rp + 4));
        f32x4 x2 = *((const f32x4*)(rp + 32));
        f32x4 x3 = *((const f32x4*)(rp + 36));
        union { unsigned u[4]; short8 s8; } ua0, ua1;
        ua0.u[0] = cvt_pk_bf16(x0[0], x0[1]);
        ua0.u[1] = cvt_pk_bf16(x0[2], x0[3]);
        ua0.u[2] = cvt_pk_bf16(x1[0], x1[1]);
        ua0.u[3] = cvt_pk_bf16(x1[2], x1[3]);
        ua1.u[0] = cvt_pk_bf16(x2[0], x2[1]);
        ua1.u[1] = cvt_pk_bf16(x2[2], x2[3]);
        ua1.u[2] = cvt_pk_bf16(x3[0], x3[1]);
        ua1.u[3] = cvt_pk_bf16(x3[2], x3[3]);
        f32x4 c0 = {0.f, 0.f, 0.f, 0.f}, c1 = {0.f, 0.f, 0.f, 0.f};
        c0 = __builtin_amdgcn_mfma_f32_16x16x32_bf16(ua0.s8, bfrag[0][0], c0, 0, 0, 0);
        c0 = __builtin_amdgcn_mfma_f32_16x16x32_bf16(ua1.s8, bfrag[0][1], c0, 0, 0, 0);
        c1 = __builtin_amdgcn_mfma_f32_16x16x32_bf16(ua0.s8, bfrag[1][0], c1, 0, 0, 0);
        c1 = __builtin_amdgcn_mfma_f32_16x16x32_bf16(ua1.s8, bfrag[1][1], c1, 0, 0, 0);
        float ps[4], pt[4];
        #pragma unroll
        for (int r = 0; r < 4; ++r) {
            int m = mt * 16 + quad * 4 + r;
            h_t[l15 * HSTR + m]        = f2bf(c0[r]);
            h_t[(l15 + 16) * HSTR + m] = f2bf(c1[r]);
            ps[r] = c0[r] * as_lo + c1[r] * as_hi;
            pt[r] = c0[r] * at_lo + c1[r] * at_hi;
        }
        #pragma unroll
        for (int off = 1; off <= 8; off <<= 1) {
            #pragma unroll
            for (int r = 0; r < 4; ++r) {
                ps[r] += __shfl_xor(ps[r], off, 64);
                pt[r] += __shfl_xor(pt[r], off, 64);
            }
        }
        if (l15 < 4) {
            int r = l15;
            int m = mt * 16 + quad * 4 + r;
            float s = ps[r], tt = pt[r];
            e1s[m] = expf(s);   e2s[m] = expf(0.2f * s);
            e1t[m] = expf(tt);  e2t[m] = expf(0.2f * tt);
        }
    }
    __syncthreads();

    // ---------- Phase B: numerator MFMA (w built in-register) + fp32 denominator ----------
    float t1[4], t2[4];
    int iR[4];
    #pragma unroll
    for (int rt = 0; rt < 4; ++rt) {
        int rw = (wv * 4 + rt) * 16 + l15;
        iR[rt] = rw;
        t1[rt] = e1t[rw]; t2[rt] = e2t[rw];
    }
    f32x4 acc[4][2];
    float dacc[4];
    #pragma unroll
    for (int rt = 0; rt < 4; ++rt) {
        acc[rt][0] = (f32x4){0.f, 0.f, 0.f, 0.f};
        acc[rt][1] = (f32x4){0.f, 0.f, 0.f, 0.f};
        dacc[rt] = 0.f;
    }

    for (int kb = 0; kb < 16; ++kb) {
        const int j0 = kb * 32 + quad * 8;
        f32x4 ev0 = *(const f32x4*)&e1s[j0], ev1 = *(const f32x4*)&e1s[j0 + 4];
        f32x4 fv0 = *(const f32x4*)&e2s[j0], fv1 = *(const f32x4*)&e2s[j0 + 4];
        short8 b0 = *(const short8*)&h_t[l15 * HSTR + j0];
        short8 b1 = *(const short8*)&h_t[(l15 + 16) * HSTR + j0];
        if ((kb >> 1) == wv) {
            // SLOW path (2 of 16 kb's): this wave's rows may self-intersect this j-block
            #pragma unroll
            for (int rt = 0; rt < 4; ++rt) {
                const bool selfkb = (kb == ((wv * 4 + rt) >> 1));
                float w8[8];
                #pragma unroll
                for (int jj = 0; jj < 8; ++jj) {
                    float e1 = (jj < 4) ? ev0[jj & 3] : ev1[jj & 3];
                    float e2 = (jj < 4) ? fv0[jj & 3] : fv1[jj & 3];
                    float w = fmaxf(t1[rt] * e1, t2[rt] * e2);
                    if (selfkb && (j0 + jj == iR[rt])) w = 0.f;
                    w8[jj] = w;
                }
                dacc[rt] += ((w8[0] + w8[1]) + (w8[2] + w8[3]))
                          + ((w8[4] + w8[5]) + (w8[6] + w8[7]));
                union { unsigned u[4]; short8 s8; } au;
                #pragma unroll
                for (int pp = 0; pp < 4; ++pp)
                    au.u[pp] = cvt_pk_bf16(w8[2 * pp], w8[2 * pp + 1]);
                acc[rt][0] = __builtin_amdgcn_mfma_f32_16x16x32_bf16(au.s8, b0, acc[rt][0], 0, 0, 0);
                acc[rt][1] = __builtin_amdgcn_mfma_f32_16x16x32_bf16(au.s8, b1, acc[rt][1], 0, 0, 0);
            }
        } else {
            // FAST path (14 of 16): no self element possible — no per-jj mask
            #pragma unroll
            for (int rt = 0; rt < 4; ++rt) {
                float w8[8];
                #pragma unroll
                for (int jj = 0; jj < 8; ++jj) {
                    float e1 = (jj < 4) ? ev0[jj & 3] : ev1[jj & 3];
                    float e2 = (jj < 4) ? fv0[jj & 3] : fv1[jj & 3];
                    w8[jj] = fmaxf(t1[rt] * e1, t2[rt] * e2);
                }
                dacc[rt] += ((w8[0] + w8[1]) + (w8[2] + w8[3]))
                          + ((w8[4] + w8[5]) + (w8[6] + w8[7]));
                union { unsigned u[4]; short8 s8; } au;
                #pragma unroll
                for (int pp = 0; pp < 4; ++pp)
                    au.u[pp] = cvt_pk_bf16(w8[2 * pp], w8[2 * pp + 1]);
                acc[rt][0] = __builtin_amdgcn_mfma_f32_16x16x32_bf16(au.s8, b0, acc[rt][0], 0, 0, 0);
                acc[rt][1] = __builtin_amdgcn_mfma_f32_16x16x32_bf16(au.s8, b1, acc[rt][1], 0, 0, 0);
            }
        }
    }

    // denominator: reduce the 4 quads (same row lives in lanes sharing l15)
    #pragma unroll
    for (int rt = 0; rt < 4; ++rt) {
        float D = dacc[rt];
        D += __shfl_xor(D, 16, 64);
        D += __shfl_xor(D, 32, 64);
        if (quad == 0) dinv[iR[rt]] = 0.125f / D;   // fold 1/H; same-wave read below
    }

    float* mbase = msgs8 + (size_t)blockIdx.x * (NN * DH);
    #pragma unroll
    for (int rt = 0; rt < 4; ++rt) {
        #pragma unroll
        for (int half = 0; half < 2; ++half) {
            #pragma unroll
            for (int r = 0; r < 4; ++r) {
                int row = (wv * 4 + rt) * 16 + quad * 4 + r;
                mbase[row * DH + half * 16 + l15] = acc[rt][half][r] * dinv[row];
            }
        }
    }
}

// GRU-style gated update. 512 blocks x 256 threads, 32 rows/block (4 rows/thread).
// Occupancy raised via MORE BLOCKS (2 blocks/CU = 2 waves/SIMD), NOT bigger blocks
// (1024-thr blocks pin VGPR=64 -> spill, see R4).
__global__ __launch_bounds__(256) void gru_kernel(
    const float* __restrict__ in_g,
    const float* __restrict__ hid_g,
    const float* __restrict__ bias_g,
    const float* __restrict__ Whr, const float* __restrict__ Whi,
    const float* __restrict__ Whm,
    const float* __restrict__ Wir, const float* __restrict__ bir,
    const float* __restrict__ Wii, const float* __restrict__ bii,
    const float* __restrict__ Win, const float* __restrict__ bin_,
    const float* __restrict__ msgs8,   // [B*8][512][32], slice = b*8+h
    float* __restrict__ out_g)
{
    __shared__ float xs[32 * 100];                // cols 0..63 = x, 64..95 = tanh(msum+bias)
    __shared__ unsigned short WtL[3 * 32 * 100];  // Wt[g][k][d] bf16 (96 d's used)

    const int t = threadIdx.x;
    const int rowbase = blockIdx.x * 32;          // 512 blocks x 32 rows
    const int bslice = blockIdx.x >> 4;           // batch of this block (32 | 512)
    const int r0 = (blockIdx.x & 15) * 32;        // row offset within batch

    // stage x: 32 rows x 64 cols, f32x4 (512 vec-ops, 2 iters)
    for (int idx = t; idx < 512; idx += 256) {
        int row = idx >> 4, dq = idx & 15;
        f32x4 v = *(const f32x4*)&in_g[(size_t)(rowbase + row) * 64 + dq * 4];
        *(f32x4*)&xs[row * 100 + dq * 4] = v;
    }
    // msgv = tanh(sum_h msgs8[b*8+h] + bias), vectorized f32x4 (1 iter)
    {
        int row = t >> 3, kq = t & 7;             // 256 = 32 rows x 8 k-quads
        size_t base = (size_t)bslice * (8 * NN * DH) + (size_t)(r0 + row) * DH + kq * 4;
        f32x4 s = {0.f, 0.f, 0.f, 0.f};
        #pragma unroll
        for (int h = 0; h < 8; ++h) {
            f32x4 v = *(const f32x4*)&msgs8[base + (size_t)h * (NN * DH)];
            s.x += v.x; s.y += v.y; s.z += v.z; s.w += v.w;
        }
        const float* bg = bias_g + kq * 4;
        float* dst = &xs[row * 100 + 64 + kq * 4];
        dst[0] = tanhf(s.x + bg[0]);
        dst[1] = tanhf(s.y + bg[1]);
        dst[2] = tanhf(s.z + bg[2]);
        dst[3] = tanhf(s.w + bg[3]);
    }
    // stage weights: 3 gates x 3072, simple loops (no div/mod)
    for (int idx = t; idx < 3072; idx += 256) {
        int d = idx >> 5, k2 = idx & 31;
        WtL[(0 * 32 + k2) * 100 + d] = f2bf((d < 64) ? Wir[d * 32 + k2] : Whr[(d - 64) * 32 + k2]);
        WtL[(1 * 32 + k2) * 100 + d] = f2bf((d < 64) ? Wii[d * 32 + k2] : Whi[(d - 64) * 32 + k2]);
        WtL[(2 * 32 + k2) * 100 + d] = f2bf((d < 64) ? Win[d * 32 + k2] : Whm[(d - 64) * 32 + k2]);
    }
    __syncthreads();

    const int k = t & 31, rg = t >> 5;            // rg in 0..7, 4 rows each
    const unsigned short* wp0 = &WtL[(0 * 32 + k) * 100];
    const unsigned short* wp1 = &WtL[(1 * 32 + k) * 100];
    const unsigned short* wp2 = &WtL[(2 * 32 + k) * 100];

    float pr[4], pi[4], xn[4], hm[4];
    #pragma unroll
    for (int r = 0; r < 4; ++r) { pr[r] = 0.f; pi[r] = 0.f; xn[r] = 0.f; hm[r] = 0.f; }

    for (int d0 = 0; d0 < 64; d0 += 4) {
        short4v wr4 = *(const short4v*)&wp0[d0];
        short4v wi4 = *(const short4v*)&wp1[d0];
        short4v wn4 = *(const short4v*)&wp2[d0];
        float wr[4], wi[4], wn[4];
        #pragma unroll
        for (int jj = 0; jj < 4; ++jj) {
            wr[jj] = bf2f((unsigned short)wr4[jj]);
            wi[jj] = bf2f((unsigned short)wi4[jj]);
            wn[jj] = bf2f((unsigned short)wn4[jj]);
        }
        #pragma unroll
        for (int r = 0; r < 4; ++r) {
            f32x4 xv = *(const f32x4*)&xs[(rg * 4 + r) * 100 + d0];
            #pragma unroll
            for (int jj = 0; jj < 4; ++jj) {
                pr[r] += xv[jj] * wr[jj];
                pi[r] += xv[jj] * wi[jj];
                xn[r] += xv[jj] * wn[jj];
            }
        }
    }
    for (int d0 = 64; d0 < 96; d0 += 4) {
        short4v wr4 = *(const short4v*)&wp0[d0];
        short4v wi4 = *(const short4v*)&wp1[d0];
        short4v wn4 = *(const short4v*)&wp2[d0];
        float wr[4], wi[4], wn[4];
        #pragma unroll
        for (int jj = 0; jj < 4; ++jj) {
            wr[jj] = bf2f((unsigned short)wr4[jj]);
            wi[jj] = bf2f((unsigned short)wi4[jj]);
            wn[jj] = bf2f((unsigned short)wn4[jj]);
        }
        #pragma unroll
        for (int r = 0; r < 4; ++r) {
            f32x4 xv = *(const f32x4*)&xs[(rg * 4 + r) * 100 + d0];
            #pragma unroll
            for (int jj = 0; jj < 4; ++jj) {
                pr[r] += xv[jj] * wr[jj];
                pi[r] += xv[jj] * wi[jj];
                hm[r] += xv[jj] * wn[jj];
            }
        }
    }

    const float bir_k = bir[k], bii_k = bii[k], bin_k = bin_[k];
    #pragma unroll
    for (int r = 0; r < 4; ++r) {
        int row = rowbase + rg * 4 + r;
        float m  = 1.f / (1.f + expf(-(pr[r] + bir_k)));
        float ig = 1.f / (1.f + expf(-(pi[r] + bii_k)));
        float nn = tanhf(xn[r] + bin_k + m * hm[r]);
        float ho = hid_g[(size_t)row * 32 + k];
        out_g[(size_t)row * 32 + k] = ig * nn + (1.f - ig) * ho;
    }
}

extern "C" void kernel_launch(void* const* d_in, const int* in_sizes, int n_in,
                              void* d_out, int out_size, void* d_ws, size_t ws_size,
                              hipStream_t stream)
{
    const float* inputs = (const float*)d_in[0];
    const float* hidden = (const float*)d_in[1];
    const float* linear = (const float*)d_in[2];
    const float* bias   = (const float*)d_in[3];
    const float* asrc   = (const float*)d_in[4];
    const float* atar   = (const float*)d_in[5];
    const float* Whr    = (const float*)d_in[6];
    const float* Whi    = (const float*)d_in[7];
    const float* Whm    = (const float*)d_in[8];
    const float* Wir    = (const float*)d_in[9];
    const float* bir    = (const float*)d_in[10];
    const float* Wii    = (const float*)d_in[11];
    const float* bii    = (const float*)d_in[12];
    const float* Win    = (const float*)d_in[13];
    const float* bin_   = (const float*)d_in[14];

    float* msgs8 = (float*)d_ws;   // [B*8][512][32] fp32, 16 MB
    attn_kernel<<<dim3(256), dim3(512), 0, stream>>>(inputs, linear, asrc, atar, msgs8);
    gru_kernel<<<dim3(512), dim3(256), 0, stream>>>(inputs, hidden, bias,
                                                    Whr, Whi, Whm,
                                                    Wir, bir, Wii, bii, Win, bin_,
                                                    msgs8, (float*)d_out);
}

// Round 10
// 116.212 us; speedup vs baseline: 1.1596x; 1.0282x over previous
//
#include <hip/hip_runtime.h>

#define NN 512
#define DIN 64
#define DH 32
#define HSTR 520   // h_t row stride (pad: 260 dw == 4 mod 32, keeps 16B alignment)

typedef __attribute__((ext_vector_type(8))) short short8;
typedef __attribute__((ext_vector_type(4))) short short4v;
typedef __attribute__((ext_vector_type(4))) float f32x4;

__device__ __forceinline__ float bf2f(unsigned short u) {
    return __uint_as_float(((unsigned)u) << 16);
}
__device__ __forceinline__ unsigned short f2bf(float x) {
    unsigned u = __float_as_uint(x);
    u += 0x7FFF + ((u >> 16) & 1);
    return (unsigned short)(u >> 16);
}
// packed RNE f32x2 -> bf16x2 (1 VALU op vs ~4 for scalar f2bf; same rounding)
__device__ __forceinline__ unsigned cvt_pk_bf16(float lo, float hi) {
    unsigned r;
    asm("v_cvt_pk_bf16_f32 %0, %1, %2" : "=v"(r) : "v"(lo), "v"(hi));
    return r;
}

// One block per (head, batch). 512 threads = 8 waves. R5-proven grid.
// TOOLCHAIN RULE (verified twice, R2-R4): 1024-thread blocks pin VGPR=64 regardless
// of __launch_bounds__ 2nd arg -> massive scratch spill. Never use 1024-thr blocks.
// VALU diet ladder (phase B is VALU-issue-bound; each ~25% cut ~ -3us):
//  R8: exp(lrelu(s+t)) == max(e^t e^s, e^.2t e^.2s); cvt_pk pack        [-3.0us]
//  R9: self-mask peeled to 2/16 kb; phase-A cvt_pk                      [-3.6us]
//  R10: ROW-SCALE CANCELLATION — softmax is invariant to per-row scale:
//       w' = max(e^s_j, e^{-0.8 t_i} * e^{0.2 s_j})  (2 VALU/weight, was 3;
//       i-side needs only rhot[] = e^{-0.8t}, e1t/e2t arrays gone)
__global__ __launch_bounds__(512) void attn_kernel(
    const float* __restrict__ in_g,    // [B,512,64]
    const float* __restrict__ lin_g,   // [H,64,32]
    const float* __restrict__ asrc_g,  // [H,32]
    const float* __restrict__ atar_g,  // [H,32]
    float* __restrict__ msgs8)         // [B*8][512][32] fp32, slice = blockIdx.x
{
    __shared__ unsigned short h_t[DH * HSTR];       // 33280 B: h_t[c*HSTR + m] = h[m][c]
    __shared__ float e1s[NN], e2s[NN];              // j-side: e^s, e^{0.2s}
    __shared__ float rhot[NN];                      // i-side: e^{-0.8 t}
    __shared__ float dinv[NN];

    const int t = threadIdx.x;
    const int lane = t & 63, wv = t >> 6;
    const int l15 = lane & 15, quad = lane >> 4;
    const int hIdx = blockIdx.x & 7, bIdx = blockIdx.x >> 3;

    const float as_lo = asrc_g[hIdx * 32 + l15];
    const float as_hi = asrc_g[hIdx * 32 + l15 + 16];
    const float at_lo = atar_g[hIdx * 32 + l15];
    const float at_hi = atar_g[hIdx * 32 + l15 + 16];

    // ---------- Phase A: projection h = x @ W via MFMA ----------
    short8 bfrag[2][2];
    {
        const float* lp = lin_g + hIdx * (DIN * DH);
        for (int nt = 0; nt < 2; ++nt)
            for (int ks = 0; ks < 2; ++ks) {
                union { unsigned u[4]; short8 s8; } bu;
                #pragma unroll
                for (int jp = 0; jp < 4; ++jp) {
                    float lo = lp[(ks * 32 + quad * 8 + 2 * jp)     * DH + l15 + nt * 16];
                    float hi = lp[(ks * 32 + quad * 8 + 2 * jp + 1) * DH + l15 + nt * 16];
                    bu.u[jp] = cvt_pk_bf16(lo, hi);
                }
                bfrag[nt][ks] = bu.s8;
            }
    }
    const float* xb = in_g + (size_t)bIdx * (NN * DIN);
    for (int mi = 0; mi < 4; ++mi) {
        int mt = wv * 4 + mi;
        int row = mt * 16 + l15;
        const float* rp = xb + row * DIN + quad * 8;
        f32x4 x0 = *((const f32x4*)rp);
        f32x4 x1 = *((const f32x4*)(rp + 4));
        f32x4 x2 = *((const f32x4*)(rp + 32));
        f32x4 x3 = *((const f32x4*)(rp + 36));
        union { unsigned u[4]; short8 s8; } ua0, ua1;
        ua0.u[0] = cvt_pk_bf16(x0[0], x0[1]);
        ua0.u[1] = cvt_pk_bf16(x0[2], x0[3]);
        ua0.u[2] = cvt_pk_bf16(x1[0], x1[1]);
        ua0.u[3] = cvt_pk_bf16(x1[2], x1[3]);
        ua1.u[0] = cvt_pk_bf16(x2[0], x2[1]);
        ua1.u[1] = cvt_pk_bf16(x2[2], x2[3]);
        ua1.u[2] = cvt_pk_bf16(x3[0], x3[1]);
        ua1.u[3] = cvt_pk_bf16(x3[2], x3[3]);
        f32x4 c0 = {0.f, 0.f, 0.f, 0.f}, c1 = {0.f, 0.f, 0.f, 0.f};
        c0 = __builtin_amdgcn_mfma_f32_16x16x32_bf16(ua0.s8, bfrag[0][0], c0, 0, 0, 0);
        c0 = __builtin_amdgcn_mfma_f32_16x16x32_bf16(ua1.s8, bfrag[0][1], c0, 0, 0, 0);
        c1 = __builtin_amdgcn_mfma_f32_16x16x32_bf16(ua0.s8, bfrag[1][0], c1, 0, 0, 0);
        c1 = __builtin_amdgcn_mfma_f32_16x16x32_bf16(ua1.s8, bfrag[1][1], c1, 0, 0, 0);
        float ps[4], pt[4];
        #pragma unroll
        for (int r = 0; r < 4; ++r) {
            int m = mt * 16 + quad * 4 + r;
            h_t[l15 * HSTR + m]        = f2bf(c0[r]);
            h_t[(l15 + 16) * HSTR + m] = f2bf(c1[r]);
            ps[r] = c0[r] * as_lo + c1[r] * as_hi;
            pt[r] = c0[r] * at_lo + c1[r] * at_hi;
        }
        #pragma unroll
        for (int off = 1; off <= 8; off <<= 1) {
            #pragma unroll
            for (int r = 0; r < 4; ++r) {
                ps[r] += __shfl_xor(ps[r], off, 64);
                pt[r] += __shfl_xor(pt[r], off, 64);
            }
        }
        if (l15 < 4) {
            int r = l15;
            int m = mt * 16 + quad * 4 + r;
            float s = ps[r], tt = pt[r];
            e1s[m] = expf(s);   e2s[m] = expf(0.2f * s);
            rhot[m] = expf(-0.8f * tt);
        }
    }
    __syncthreads();

    // ---------- Phase B: numerator MFMA (w' built in-register) + fp32 denominator ----------
    float rho[4];
    int iR[4];
    #pragma unroll
    for (int rt = 0; rt < 4; ++rt) {
        int rw = (wv * 4 + rt) * 16 + l15;
        iR[rt] = rw;
        rho[rt] = rhot[rw];
    }
    f32x4 acc[4][2];
    float dacc[4];
    #pragma unroll
    for (int rt = 0; rt < 4; ++rt) {
        acc[rt][0] = (f32x4){0.f, 0.f, 0.f, 0.f};
        acc[rt][1] = (f32x4){0.f, 0.f, 0.f, 0.f};
        dacc[rt] = 0.f;
    }

    for (int kb = 0; kb < 16; ++kb) {
        const int j0 = kb * 32 + quad * 8;
        f32x4 ev0 = *(const f32x4*)&e1s[j0], ev1 = *(const f32x4*)&e1s[j0 + 4];
        f32x4 fv0 = *(const f32x4*)&e2s[j0], fv1 = *(const f32x4*)&e2s[j0 + 4];
        short8 b0 = *(const short8*)&h_t[l15 * HSTR + j0];
        short8 b1 = *(const short8*)&h_t[(l15 + 16) * HSTR + j0];
        if ((kb >> 1) == wv) {
            // SLOW path (2 of 16 kb's): this wave's rows may self-intersect this j-block
            #pragma unroll
            for (int rt = 0; rt < 4; ++rt) {
                const bool selfkb = (kb == ((wv * 4 + rt) >> 1));
                float w8[8];
                #pragma unroll
                for (int jj = 0; jj < 8; ++jj) {
                    float e1 = (jj < 4) ? ev0[jj & 3] : ev1[jj & 3];
                    float e2 = (jj < 4) ? fv0[jj & 3] : fv1[jj & 3];
                    float w = fmaxf(e1, rho[rt] * e2);
                    if (selfkb && (j0 + jj == iR[rt])) w = 0.f;
                    w8[jj] = w;
                }
                dacc[rt] += ((w8[0] + w8[1]) + (w8[2] + w8[3]))
                          + ((w8[4] + w8[5]) + (w8[6] + w8[7]));
                union { unsigned u[4]; short8 s8; } au;
                #pragma unroll
                for (int pp = 0; pp < 4; ++pp)
                    au.u[pp] = cvt_pk_bf16(w8[2 * pp], w8[2 * pp + 1]);
                acc[rt][0] = __builtin_amdgcn_mfma_f32_16x16x32_bf16(au.s8, b0, acc[rt][0], 0, 0, 0);
                acc[rt][1] = __builtin_amdgcn_mfma_f32_16x16x32_bf16(au.s8, b1, acc[rt][1], 0, 0, 0);
            }
        } else {
            // FAST path (14 of 16): no self element possible — no per-jj mask
            #pragma unroll
            for (int rt = 0; rt < 4; ++rt) {
                float w8[8];
                #pragma unroll
                for (int jj = 0; jj < 8; ++jj) {
                    float e1 = (jj < 4) ? ev0[jj & 3] : ev1[jj & 3];
                    float e2 = (jj < 4) ? fv0[jj & 3] : fv1[jj & 3];
                    w8[jj] = fmaxf(e1, rho[rt] * e2);
                }
                dacc[rt] += ((w8[0] + w8[1]) + (w8[2] + w8[3]))
                          + ((w8[4] + w8[5]) + (w8[6] + w8[7]));
                union { unsigned u[4]; short8 s8; } au;
                #pragma unroll
                for (int pp = 0; pp < 4; ++pp)
                    au.u[pp] = cvt_pk_bf16(w8[2 * pp], w8[2 * pp + 1]);
                acc[rt][0] = __builtin_amdgcn_mfma_f32_16x16x32_bf16(au.s8, b0, acc[rt][0], 0, 0, 0);
                acc[rt][1] = __builtin_amdgcn_mfma_f32_16x16x32_bf16(au.s8, b1, acc[rt][1], 0, 0, 0);
            }
        }
    }

    // denominator: reduce the 4 quads (same row lives in lanes sharing l15)
    #pragma unroll
    for (int rt = 0; rt < 4; ++rt) {
        float D = dacc[rt];
        D += __shfl_xor(D, 16, 64);
        D += __shfl_xor(D, 32, 64);
        if (quad == 0) dinv[iR[rt]] = 0.125f / D;   // fold 1/H; same-wave read below
    }

    float* mbase = msgs8 + (size_t)blockIdx.x * (NN * DH);
    #pragma unroll
    for (int rt = 0; rt < 4; ++rt) {
        #pragma unroll
        for (int half = 0; half < 2; ++half) {
            #pragma unroll
            for (int r = 0; r < 4; ++r) {
                int row = (wv * 4 + rt) * 16 + quad * 4 + r;
                mbase[row * DH + half * 16 + l15] = acc[rt][half][r] * dinv[row];
            }
        }
    }
}

// GRU-style gated update. 512 blocks x 256 threads, 32 rows/block (4 rows/thread).
// Occupancy raised via MORE BLOCKS (2 blocks/CU = 2 waves/SIMD), NOT bigger blocks
// (1024-thr blocks pin VGPR=64 -> spill, see R4).
__global__ __launch_bounds__(256) void gru_kernel(
    const float* __restrict__ in_g,
    const float* __restrict__ hid_g,
    const float* __restrict__ bias_g,
    const float* __restrict__ Whr, const float* __restrict__ Whi,
    const float* __restrict__ Whm,
    const float* __restrict__ Wir, const float* __restrict__ bir,
    const float* __restrict__ Wii, const float* __restrict__ bii,
    const float* __restrict__ Win, const float* __restrict__ bin_,
    const float* __restrict__ msgs8,   // [B*8][512][32], slice = b*8+h
    float* __restrict__ out_g)
{
    __shared__ float xs[32 * 100];                // cols 0..63 = x, 64..95 = tanh(msum+bias)
    __shared__ unsigned short WtL[3 * 32 * 100];  // Wt[g][k][d] bf16 (96 d's used)

    const int t = threadIdx.x;
    const int rowbase = blockIdx.x * 32;          // 512 blocks x 32 rows
    const int bslice = blockIdx.x >> 4;           // batch of this block (32 | 512)
    const int r0 = (blockIdx.x & 15) * 32;        // row offset within batch

    // stage x: 32 rows x 64 cols, f32x4 (512 vec-ops, 2 iters)
    for (int idx = t; idx < 512; idx += 256) {
        int row = idx >> 4, dq = idx & 15;
        f32x4 v = *(const f32x4*)&in_g[(size_t)(rowbase + row) * 64 + dq * 4];
        *(f32x4*)&xs[row * 100 + dq * 4] = v;
    }
    // msgv = tanh(sum_h msgs8[b*8+h] + bias), vectorized f32x4 (1 iter)
    {
        int row = t >> 3, kq = t & 7;             // 256 = 32 rows x 8 k-quads
        size_t base = (size_t)bslice * (8 * NN * DH) + (size_t)(r0 + row) * DH + kq * 4;
        f32x4 s = {0.f, 0.f, 0.f, 0.f};
        #pragma unroll
        for (int h = 0; h < 8; ++h) {
            f32x4 v = *(const f32x4*)&msgs8[base + (size_t)h * (NN * DH)];
            s.x += v.x; s.y += v.y; s.z += v.z; s.w += v.w;
        }
        const float* bg = bias_g + kq * 4;
        float* dst = &xs[row * 100 + 64 + kq * 4];
        dst[0] = tanhf(s.x + bg[0]);
        dst[1] = tanhf(s.y + bg[1]);
        dst[2] = tanhf(s.z + bg[2]);
        dst[3] = tanhf(s.w + bg[3]);
    }
    // stage weights: 3 gates x 3072, simple loops (no div/mod)
    for (int idx = t; idx < 3072; idx += 256) {
        int d = idx >> 5, k2 = idx & 31;
        WtL[(0 * 32 + k2) * 100 + d] = f2bf((d < 64) ? Wir[d * 32 + k2] : Whr[(d - 64) * 32 + k2]);
        WtL[(1 * 32 + k2) * 100 + d] = f2bf((d < 64) ? Wii[d * 32 + k2] : Whi[(d - 64) * 32 + k2]);
        WtL[(2 * 32 + k2) * 100 + d] = f2bf((d < 64) ? Win[d * 32 + k2] : Whm[(d - 64) * 32 + k2]);
    }
    __syncthreads();

    const int k = t & 31, rg = t >> 5;            // rg in 0..7, 4 rows each
    const unsigned short* wp0 = &WtL[(0 * 32 + k) * 100];
    const unsigned short* wp1 = &WtL[(1 * 32 + k) * 100];
    const unsigned short* wp2 = &WtL[(2 * 32 + k) * 100];

    float pr[4], pi[4], xn[4], hm[4];
    #pragma unroll
    for (int r = 0; r < 4; ++r) { pr[r] = 0.f; pi[r] = 0.f; xn[r] = 0.f; hm[r] = 0.f; }

    for (int d0 = 0; d0 < 64; d0 += 4) {
        short4v wr4 = *(const short4v*)&wp0[d0];
        short4v wi4 = *(const short4v*)&wp1[d0];
        short4v wn4 = *(const short4v*)&wp2[d0];
        float wr[4], wi[4], wn[4];
        #pragma unroll
        for (int jj = 0; jj < 4; ++jj) {
            wr[jj] = bf2f((unsigned short)wr4[jj]);
            wi[jj] = bf2f((unsigned short)wi4[jj]);
            wn[jj] = bf2f((unsigned short)wn4[jj]);
        }
        #pragma unroll
        for (int r = 0; r < 4; ++r) {
            f32x4 xv = *(const f32x4*)&xs[(rg * 4 + r) * 100 + d0];
            #pragma unroll
            for (int jj = 0; jj < 4; ++jj) {
                pr[r] += xv[jj] * wr[jj];
                pi[r] += xv[jj] * wi[jj];
                xn[r] += xv[jj] * wn[jj];
            }
        }
    }
    for (int d0 = 64; d0 < 96; d0 += 4) {
        short4v wr4 = *(const short4v*)&wp0[d0];
        short4v wi4 = *(const short4v*)&wp1[d0];
        short4v wn4 = *(const short4v*)&wp2[d0];
        float wr[4], wi[4], wn[4];
        #pragma unroll
        for (int jj = 0; jj < 4; ++jj) {
            wr[jj] = bf2f((unsigned short)wr4[jj]);
            wi[jj] = bf2f((unsigned short)wi4[jj]);
            wn[jj] = bf2f((unsigned short)wn4[jj]);
        }
        #pragma unroll
        for (int r = 0; r < 4; ++r) {
            f32x4 xv = *(const f32x4*)&xs[(rg * 4 + r) * 100 + d0];
            #pragma unroll
            for (int jj = 0; jj < 4; ++jj) {
                pr[r] += xv[jj] * wr[jj];
                pi[r] += xv[jj] * wi[jj];
                hm[r] += xv[jj] * wn[jj];
            }
        }
    }

    const float bir_k = bir[k], bii_k = bii[k], bin_k = bin_[k];
    #pragma unroll
    for (int r = 0; r < 4; ++r) {
        int row = rowbase + rg * 4 + r;
        float m  = 1.f / (1.f + expf(-(pr[r] + bir_k)));
        float ig = 1.f / (1.f + expf(-(pi[r] + bii_k)));
        float nn = tanhf(xn[r] + bin_k + m * hm[r]);
        float ho = hid_g[(size_t)row * 32 + k];
        out_g[(size_t)row * 32 + k] = ig * nn + (1.f - ig) * ho;
    }
}

extern "C" void kernel_launch(void* const* d_in, const int* in_sizes, int n_in,
                              void* d_out, int out_size, void* d_ws, size_t ws_size,
                              hipStream_t stream)
{
    const float* inputs = (const float*)d_in[0];
    const float* hidden = (const float*)d_in[1];
    const float* linear = (const float*)d_in[2];
    const float* bias   = (const float*)d_in[3];
    const float* asrc   = (const float*)d_in[4];
    const float* atar   = (const float*)d_in[5];
    const float* Whr    = (const float*)d_in[6];
    const float* Whi    = (const float*)d_in[7];
    const float* Whm    = (const float*)d_in[8];
    const float* Wir    = (const float*)d_in[9];
    const float* bir    = (const float*)d_in[10];
    const float* Wii    = (const float*)d_in[11];
    const float* bii    = (const float*)d_in[12];
    const float* Win    = (const float*)d_in[13];
    const float* bin_   = (const float*)d_in[14];

    float* msgs8 = (float*)d_ws;   // [B*8][512][32] fp32, 16 MB
    attn_kernel<<<dim3(256), dim3(512), 0, stream>>>(inputs, linear, asrc, atar, msgs8);
    gru_kernel<<<dim3(512), dim3(256), 0, stream>>>(inputs, hidden, bias,
                                                    Whr, Whi, Whm,
                                                    Wir, bir, Wii, bii, Win, bin_,
                                                    msgs8, (float*)d_out);
}